// Round 4
// baseline (577.556 us; speedup 1.0000x reference)
//
#include <hip/hip_runtime.h>
#include <math.h>

#define TT 250
#define BT 256
#define HN 128
#define ON 20
#define KIN 700
#define NKT 22

// ws layout (float offsets): xin[250*256*128] | packed W hi | packed W lo
#define XIN_OFF 0
#define WPKH_OFF 8192000   // 45056 floats (90112 bf16)
#define WPKL_OFF 8237056   // 45056 floats

typedef __attribute__((ext_vector_type(8))) short bf16x8;
typedef __attribute__((ext_vector_type(4))) float f32x4;

__device__ __forceinline__ unsigned short bf16rne(float f) {
    unsigned u = __float_as_uint(f);
    unsigned r = u + 0x7fffu + ((u >> 16) & 1u);
    return (unsigned short)(r >> 16);
}
__device__ __forceinline__ void hilo(float v, short& h, short& l) {
    unsigned short hh = bf16rne(v);
    float vh = __uint_as_float((unsigned)hh << 16);
    h = (short)hh;
    l = (short)bf16rne(v - vh);
}

// async global->LDS, 16B per lane. LDS dest is wave-uniform base + lane*16;
// global src is per-lane (guide §5 / m97).
__device__ __forceinline__ void gl_lds16(const void* g, void* l) {
    __builtin_amdgcn_global_load_lds(
        (const __attribute__((address_space(1))) unsigned int*)g,
        (__attribute__((address_space(3))) unsigned int*)l, 16, 0, 0);
}

// ---------------------------------------------------------------------------
// pack w_ih1 (700x128, zero-pad K to 704) into MFMA B-frag order, hi/lo bf16.
// ---------------------------------------------------------------------------
__global__ __launch_bounds__(256) void packw(const float* __restrict__ w,
                                             unsigned short* __restrict__ ph,
                                             unsigned short* __restrict__ pl) {
    int i = blockIdx.x * 256 + threadIdx.x;   // 352*256 = 90112 = 704*128
    int k = i >> 7, c = i & 127;
    float v = (k < KIN) ? w[k * HN + c] : 0.f;
    short h, l;
    hilo(v, h, l);
    int dst = (((k >> 5) * 8 + (c >> 4)) * 64 + (((k >> 3) & 3) * 16 + (c & 15))) * 8 + (k & 7);
    ph[dst] = (unsigned short)h;
    pl[dst] = (unsigned short)l;
}

// ---------------------------------------------------------------------------
// input projection v4: COALESCED x via LDS staging. 500 blocks x 512 thr
// (8 waves, 16 rows each). Per kt both the 16KB weight tile AND the 16KB
// x-tile (128 rows x 32 floats) are staged with global_load_lds from
// coalesced sources. x LDS layout is XOR-swizzled (byte ^= (row&7)<<4) to
// make the 128B-stride fragment reads conflict-free; the swizzle is applied
// by pre-permuting the global SOURCE (m173 pattern) since gl_lds dests are
// linear. Tail k=700..703: source clamped to valid floats (finite), weight
// pad is 0 => contributes exactly +0.0 (same as v3's zeroed av). Numerics
// bitwise-identical to v3.
// ---------------------------------------------------------------------------
__global__ __launch_bounds__(512, 2) void gemm_in(const float* __restrict__ x,
        const unsigned short* __restrict__ wph, const unsigned short* __restrict__ wpl,
        const float* __restrict__ bias1, const float* __restrict__ bias2,
        float* __restrict__ xin) {
    __shared__ __align__(16) unsigned char wbuf[2][16384];
    __shared__ __align__(16) unsigned char xbuf[2][16384];
    const int tid = threadIdx.x;
    const int w = tid >> 6, lane = tid & 63;
    const int q = lane >> 4, li = lane & 15;
    const long mbase = (long)blockIdx.x * 128;

    // staging geometry (per thread, constant across kt)
    const int xrow1 = tid >> 3;            // rows 0..63
    const int xrow2 = xrow1 + 64;          // rows 64..127
    const int xcs1 = (tid & 7) ^ (xrow1 & 7);   // source col16 for chunk tid
    const int xcs2 = (tid & 7) ^ (xrow2 & 7);   // source col16 for chunk tid+512
    const int wbase = w * 1024;

    f32x4 acc[8];
#pragma unroll
    for (int nt = 0; nt < 8; nt++) acc[nt] = (f32x4){0.f, 0.f, 0.f, 0.f};

    auto stage = [&](int kt, int buf) {
        char* wb = (char*)wbuf[buf];
        char* xb = (char*)xbuf[buf];
        gl_lds16((const char*)wph + kt * 8192 + tid * 16, wb + wbase);
        gl_lds16((const char*)wpl + kt * 8192 + tid * 16, wb + 8192 + wbase);
        int c1 = xcs1, c2 = xcs2;
        if (kt == NKT - 1) {               // k 700..703 OOB -> re-read valid col
            if (c1 == 7) c1 = 6;
            if (c2 == 7) c2 = 6;
        }
        gl_lds16((const char*)x + (mbase + xrow1) * (KIN * 4) + kt * 128 + c1 * 16,
                 xb + wbase);
        gl_lds16((const char*)x + (mbase + xrow2) * (KIN * 4) + kt * 128 + c2 * 16,
                 xb + 8192 + wbase);
    };

    stage(0, 0);
    __syncthreads();   // drains stage(0)

    // fragment read address in the swizzled x tile (addr^16 gives elems 4..7)
    const int xaddr = (w * 16 + li) * 128 + ((q * 32) ^ ((li & 7) << 4));

    for (int kt = 0; kt < NKT; kt++) {
        if (kt + 1 < NKT) stage(kt + 1, (kt + 1) & 1);

        const char* xc = (const char*)xbuf[kt & 1];
        float av[8];
        *(float4*)&av[0] = *(const float4*)(xc + xaddr);
        *(float4*)&av[4] = *(const float4*)(xc + (xaddr ^ 16));

        bf16x8 ah, al;
#pragma unroll
        for (int j = 0; j < 8; j++) {
            short h, l;
            hilo(av[j], h, l);
            ah[j] = h; al[j] = l;
        }

        const bf16x8* cv = (const bf16x8*)&wbuf[kt & 1][0];
#pragma unroll
        for (int nt = 0; nt < 8; nt++) {
            bf16x8 bh = cv[nt * 64 + lane];
            bf16x8 bl = cv[512 + nt * 64 + lane];
            acc[nt] = __builtin_amdgcn_mfma_f32_16x16x32_bf16(ah, bh, acc[nt], 0, 0, 0);
            acc[nt] = __builtin_amdgcn_mfma_f32_16x16x32_bf16(al, bh, acc[nt], 0, 0, 0);
            acc[nt] = __builtin_amdgcn_mfma_f32_16x16x32_bf16(ah, bl, acc[nt], 0, 0, 0);
        }
        __syncthreads();
    }

    // epilogue: biases folded in here (b_ih1 + b_h1h1)
    float b12[8];
#pragma unroll
    for (int nt = 0; nt < 8; nt++) {
        int c = nt * 16 + li;
        b12[nt] = bias1[c] + bias2[c];
    }
#pragma unroll
    for (int r = 0; r < 4; r++) {
        long m = mbase + w * 16 + q * 4 + r;
        int bq = (int)(((unsigned long long)m * 67109ull) >> 24);  // m/250, exact for m<3.2M
        int tt = (int)m - bq * 250;
        float* dst = xin + ((size_t)tt * BT + bq) * HN;
#pragma unroll
        for (int nt = 0; nt < 8; nt++) dst[nt * 16 + li] = acc[nt][r] + b12[nt];
    }
}

// ---------------------------------------------------------------------------
// scan v9: v8 single-barrier skeleton + LO WEIGHT FRAGS IN LDS.
// Theory: with (512,2) the 128 weight regs live in AGPRs and the compiler
// inserts v_accvgpr_read copies before each MFMA (~192 VALU/step/wave,
// matching the unexplained VALUBusy). Moving the 4 lo arrays (64 regs) to
// LDS (re-read per step, ~30cyc of LDS BW) removes most AGPR pressure.
// Chains reordered aJ/aG (+aO) before aI so LIF2's inputs finish first.
// Per-accumulator MFMA order unchanged -> bitwise-identical results.
// ---------------------------------------------------------------------------
__global__ __launch_bounds__(512, 2) void snn_scan(
    const float* __restrict__ xin, const float* __restrict__ mask,
    const float* __restrict__ w_h1h1, const float* __restrict__ w_h1h2,
    const float* __restrict__ b_h1h2, const float* __restrict__ w_h2h2,
    const float* __restrict__ b_h2h2, const float* __restrict__ w_h2o,
    const float* __restrict__ b_h2o, const float* __restrict__ tau_adp1,
    const float* __restrict__ tau_adp2, const float* __restrict__ taum1,
    const float* __restrict__ taum2, const float* __restrict__ taumo,
    const float* __restrict__ h1m0, const float* __restrict__ h2m0,
    const float* __restrict__ om0, float* __restrict__ out) {

    __shared__ __align__(16) unsigned short sA1[2 * 2048];  // S1 frags, parity dbuf
    __shared__ __align__(16) unsigned short sA2[2 * 2048];  // S2 frags, parity dbuf
    __shared__ __align__(16) unsigned short sloW[8 * 3 * 4 * 64 * 8]; // lo frags 96KB
    __shared__ __align__(16) unsigned short sloO[2 * 4 * 64 * 8];     // lO (w6,w7) 8KB
    __shared__ float omb[2][16 * ON];                       // om, parity dbuf
    __shared__ float red[8];

    const int tid = threadIdx.x;
    const int w = tid >> 6, lane = tid & 63;
    const int q = lane >> 4, li = lane & 15;
    const int col = w * 16 + li;          // this lane's neuron column
    const int r0 = blockIdx.x * 16;       // batch-row base

    // ---- weight fragments: hi in registers, lo in LDS ----
    bf16x8 h11[4], h22[4], h12[4], hO[4];
    const int ocol = (w == 6) ? li : 16 + li;         // WHO col (w6: 0-15, w7: 16-19)
    const bool oval = (w >= 6) && (ocol < ON);
    bf16x8* lo11w = (bf16x8*)sloW + w * 768;          // per wave: 3 arrs x 4kt x 64
    bf16x8* lo22w = lo11w + 256;
    bf16x8* lo12w = lo11w + 512;
    bf16x8* loOw  = (bf16x8*)sloO + ((w >= 6) ? (w - 6) * 256 : 0);
    float pn = 0.f;
#pragma unroll
    for (int kt = 0; kt < 4; kt++) {
        bf16x8 L11, L22, L12, LO;
#pragma unroll
        for (int j = 0; j < 8; j++) {
            const int k = kt * 32 + q * 8 + j;
            const int idx = k * HN + col;
            float v11 = w_h1h1[idx] * mask[idx];
            float v22 = w_h2h2[idx] * mask[HN * HN + idx];
            float v12 = w_h1h2[idx];
            pn += fabsf(v11) + fabsf(v22);
            short hh, ll;
            hilo(v11, hh, ll); h11[kt][j] = hh; L11[j] = ll;
            hilo(v22, hh, ll); h22[kt][j] = hh; L22[j] = ll;
            hilo(v12, hh, ll); h12[kt][j] = hh; L12[j] = ll;
            float vO = oval ? w_h2o[k * ON + ocol] : 0.f;
            hilo(vO, hh, ll); hO[kt][j] = hh; LO[j] = ll;
        }
        lo11w[kt * 64 + lane] = L11;
        lo22w[kt * 64 + lane] = L22;
        lo12w[kt * 64 + lane] = L12;
        if (w >= 6) loOw[kt * 64 + lane] = LO;
    }

    // ---- per-lane constants & state ----
    const float a1 = expf(-1.f / taum1[col]);
    const float r1 = expf(-1.f / tau_adp1[col]);
    const float a2 = expf(-1.f / taum2[col]);
    const float r2 = expf(-1.f / tau_adp2[col]);
    const float cc2 = b_h1h2[col] + b_h2h2[col];
    float h1m[4], h2m[4], b1[4], b2[4], c1[4], c2n[4];
    unsigned s1bits = 0, s2bits = 0;
#pragma unroll
    for (int r = 0; r < 4; r++) {
        h1m[r] = h1m0[(r0 + q * 4 + r) * HN + col];
        h2m[r] = h2m0[(r0 + q * 4 + r) * HN + col];
        b1[r] = 0.01f; b2[r] = 0.01f; c1[r] = 0.f; c2n[r] = 0.f;
    }
    const float ao = oval ? expf(-1.f / taumo[ocol]) : 0.f;
    const float bo = oval ? b_h2o[ocol] : 0.f;
    float om[4];
#pragma unroll
    for (int r = 0; r < 4; r++)
        om[r] = oval ? om0[(r0 + q * 4 + r) * ON + ocol] : 0.f;
    const int sm = lane >> 2, ob = (lane & 3) * 5;    // w0 softmax roles
    float accs[5] = {0.f, 0.f, 0.f, 0.f, 0.f};

    // zero spike frags (both parity buffers)
    {
        unsigned* z1 = (unsigned*)sA1;
        unsigned* z2 = (unsigned*)sA2;
        z1[tid] = 0u; z1[tid + 512] = 0u; z1[tid + 1024] = 0u; z1[tid + 1536] = 0u;
        z2[tid] = 0u; z2[tid + 512] = 0u; z2[tid + 1024] = 0u; z2[tid + 1536] = 0u;
    }

    // A_norm: exact f32 sum of |masked| weights, each element once
#pragma unroll
    for (int off = 32; off > 0; off >>= 1) pn += __shfl_down(pn, off);
    if (lane == 0) red[w] = pn;
    __syncthreads();   // also publishes slo lo-frag writes
    if (tid == 0 && blockIdx.x == 0) {
        float s = 0.f;
#pragma unroll
        for (int i = 0; i < 8; i++) s += red[i];
        out[70656] = s;
    }

    // spike frag write index (this lane's 4 elements: +r*8)
    const int wbase = (w >> 1) * 512 + (((2 * w + (li >> 3)) & 3) * 16 + q * 4) * 8 + (li & 7);
    const unsigned short ONE = 0x3F80u;

    const bf16x8* lo11r = (const bf16x8*)sloW + w * 768;
    const bf16x8* lo22r = lo11r + 256;
    const bf16x8* lo12r = lo11r + 512;
    const bf16x8* loOr  = (const bf16x8*)sloO + ((w >= 6) ? (w - 6) * 256 : 0);

    // xin running pointer: rows r0+q*4+r, col; +BT*HN per step
    const float* xp = xin + (size_t)(r0 + q * 4) * HN + col;

    for (int i = 0; i < TT; i++) {
        const int pa = i & 1;

        // xt for LIF1(i): VMEM issued first, consumed at end of body
        float xt[4];
#pragma unroll
        for (int r = 0; r < 4; r++) xt[r] = xp[r * HN];
        xp += BT * HN;

        // frag reads: g1 = S1(i-1) [buf pa^1], f2 = S2(i-2) [buf pa]
        const bf16x8* g1p = (const bf16x8*)(sA1 + ((pa ^ 1) << 11));
        const bf16x8* f2p = (const bf16x8*)(sA2 + (pa << 11));
        bf16x8 g1[4], f2[4];
#pragma unroll
        for (int kt = 0; kt < 4; kt++) {
            g1[kt] = g1p[kt * 64 + lane];
            f2[kt] = f2p[kt * 64 + lane];
        }

        // J/G chains first (LIF2 needs them), lo-frags streamed from LDS
        f32x4 aJ = {0.f, 0.f, 0.f, 0.f}, aG = {0.f, 0.f, 0.f, 0.f};
        {
            bf16x8 t12[4], t22[4];
#pragma unroll
            for (int kt = 0; kt < 4; kt++) {
                t12[kt] = lo12r[kt * 64 + lane];
                t22[kt] = lo22r[kt * 64 + lane];
            }
#pragma unroll
            for (int kt = 0; kt < 4; kt++) {
                aJ = __builtin_amdgcn_mfma_f32_16x16x32_bf16(g1[kt], h12[kt], aJ, 0, 0, 0);
                aJ = __builtin_amdgcn_mfma_f32_16x16x32_bf16(g1[kt], t12[kt], aJ, 0, 0, 0);
                aG = __builtin_amdgcn_mfma_f32_16x16x32_bf16(f2[kt], h22[kt], aG, 0, 0, 0);
                aG = __builtin_amdgcn_mfma_f32_16x16x32_bf16(f2[kt], t22[kt], aG, 0, 0, 0);
            }
        }
        f32x4 aO = {0.f, 0.f, 0.f, 0.f};
        if (w >= 6) {
            bf16x8 tO[4];
#pragma unroll
            for (int kt = 0; kt < 4; kt++) tO[kt] = loOr[kt * 64 + lane];
#pragma unroll
            for (int kt = 0; kt < 4; kt++) {
                aO = __builtin_amdgcn_mfma_f32_16x16x32_bf16(f2[kt], hO[kt], aO, 0, 0, 0);
                aO = __builtin_amdgcn_mfma_f32_16x16x32_bf16(f2[kt], tO[kt], aO, 0, 0, 0);
            }
        }
        // I chain (LIF1 consumes it last)
        f32x4 aI = {0.f, 0.f, 0.f, 0.f};
        {
            bf16x8 t11[4];
#pragma unroll
            for (int kt = 0; kt < 4; kt++) t11[kt] = lo11r[kt * 64 + lane];
#pragma unroll
            for (int kt = 0; kt < 4; kt++) {
                aI = __builtin_amdgcn_mfma_f32_16x16x32_bf16(g1[kt], h11[kt], aI, 0, 0, 0);
                aI = __builtin_amdgcn_mfma_f32_16x16x32_bf16(g1[kt], t11[kt], aI, 0, 0, 0);
            }
        }

        // LIF2 for step i-1 (skip at i=0; S2(-1)=0 already in zeroed buffer)
        if (i >= 1) {
            unsigned short* s2w = sA2 + ((pa ^ 1) << 11);
#pragma unroll
            for (int r = 0; r < 4; r++) {
                const float sv = (float)((s2bits >> r) & 1u);
                const float i2 = aJ[r] + aG[r] + cc2;
                b2[r] = r2 * b2[r] + (1.f - r2) * sv;
                const float B = 0.01f + 1.8f * b2[r];
                h2m[r] = a2 * h2m[r] + (1.f - a2) * i2 - B * sv;
                const bool sp = (h2m[r] - B) > 0.f;
                s2bits = sp ? (s2bits | (1u << r)) : (s2bits & ~(1u << r));
                c2n[r] += sp ? 1.f : 0.f;
                s2w[wbase + r * 8] = sp ? ONE : (unsigned short)0;
            }
        }

        // om update for step i-2 (w6/7), into parity buffer pa
        if (w >= 6 && i >= 2) {
#pragma unroll
            for (int r = 0; r < 4; r++) {
                om[r] = ao * om[r] + (1.f - ao) * (bo + aO[r]);
                if (oval) omb[pa][(q * 4 + r) * ON + ocol] = om[r];
            }
        }

        // softmax accumulate for step i-3 (w0), from parity buffer pa^1
        if (w == 0 && i >= 14) {
            float v[5], e[5];
            float mx = -1e30f;
#pragma unroll
            for (int s = 0; s < 5; s++) { v[s] = omb[pa ^ 1][sm * ON + ob + s]; mx = fmaxf(mx, v[s]); }
            mx = fmaxf(mx, __shfl_xor(mx, 1));
            mx = fmaxf(mx, __shfl_xor(mx, 2));
            float se = 0.f;
#pragma unroll
            for (int s = 0; s < 5; s++) { e[s] = __expf(v[s] - mx); se += e[s]; }
            se += __shfl_xor(se, 1);
            se += __shfl_xor(se, 2);
            const float inv = 1.f / se;
#pragma unroll
            for (int s = 0; s < 5; s++) accs[s] += e[s] * inv;
        }

        // LIF1 for step i
        {
            unsigned short* s1w = sA1 + (pa << 11);
#pragma unroll
            for (int r = 0; r < 4; r++) {
                const float sv = (float)((s1bits >> r) & 1u);
                const float i1 = xt[r] + aI[r];       // biases folded into xin
                b1[r] = r1 * b1[r] + (1.f - r1) * sv;
                const float B = 0.01f + 1.8f * b1[r];
                h1m[r] = a1 * h1m[r] + (1.f - a1) * i1 - B * sv;
                const bool sp = (h1m[r] - B) > 0.f;
                s1bits = sp ? (s1bits | (1u << r)) : (s1bits & ~(1u << r));
                c1[r] += sp ? 1.f : 0.f;
                s1w[wbase + r * 8] = sp ? ONE : (unsigned short)0;
            }
        }
        __syncthreads();   // single barrier: publishes S1(i), S2(i-1), om(i-2)
    }

    // ================= epilogue =================
    // E1 (i=250): LIF2(249), om(248), softmax(247)
    {
        const bf16x8* g1p = (const bf16x8*)(sA1 + 2048);  // S1(249)
        const bf16x8* f2p = (const bf16x8*)(sA2);         // S2(248)
        bf16x8 g1[4], f2[4], t12[4], t22[4];
#pragma unroll
        for (int kt = 0; kt < 4; kt++) {
            g1[kt] = g1p[kt * 64 + lane];
            f2[kt] = f2p[kt * 64 + lane];
            t12[kt] = lo12r[kt * 64 + lane];
            t22[kt] = lo22r[kt * 64 + lane];
        }
        f32x4 aJ = {0.f, 0.f, 0.f, 0.f}, aG = {0.f, 0.f, 0.f, 0.f};
#pragma unroll
        for (int kt = 0; kt < 4; kt++) {
            aJ = __builtin_amdgcn_mfma_f32_16x16x32_bf16(g1[kt], h12[kt], aJ, 0, 0, 0);
            aJ = __builtin_amdgcn_mfma_f32_16x16x32_bf16(g1[kt], t12[kt], aJ, 0, 0, 0);
            aG = __builtin_amdgcn_mfma_f32_16x16x32_bf16(f2[kt], h22[kt], aG, 0, 0, 0);
            aG = __builtin_amdgcn_mfma_f32_16x16x32_bf16(f2[kt], t22[kt], aG, 0, 0, 0);
        }
        f32x4 aO = {0.f, 0.f, 0.f, 0.f};
        if (w >= 6) {
            bf16x8 tO[4];
#pragma unroll
            for (int kt = 0; kt < 4; kt++) tO[kt] = loOr[kt * 64 + lane];
#pragma unroll
            for (int kt = 0; kt < 4; kt++) {
                aO = __builtin_amdgcn_mfma_f32_16x16x32_bf16(f2[kt], hO[kt], aO, 0, 0, 0);
                aO = __builtin_amdgcn_mfma_f32_16x16x32_bf16(f2[kt], tO[kt], aO, 0, 0, 0);
            }
        }
        // LIF2 step 249 -> sA2 buf1
        {
            unsigned short* s2w = sA2 + 2048;
#pragma unroll
            for (int r = 0; r < 4; r++) {
                const float sv = (float)((s2bits >> r) & 1u);
                const float i2 = aJ[r] + aG[r] + cc2;
                b2[r] = r2 * b2[r] + (1.f - r2) * sv;
                const float B = 0.01f + 1.8f * b2[r];
                h2m[r] = a2 * h2m[r] + (1.f - a2) * i2 - B * sv;
                const bool sp = (h2m[r] - B) > 0.f;
                s2bits = sp ? (s2bits | (1u << r)) : (s2bits & ~(1u << r));
                c2n[r] += sp ? 1.f : 0.f;
                s2w[wbase + r * 8] = sp ? ONE : (unsigned short)0;
            }
        }
        if (w >= 6) {   // om(248) -> omb[0]
#pragma unroll
            for (int r = 0; r < 4; r++) {
                om[r] = ao * om[r] + (1.f - ao) * (bo + aO[r]);
                if (oval) omb[0][(q * 4 + r) * ON + ocol] = om[r];
            }
        }
        if (w == 0) {   // softmax step 247 from omb[1]
            float v[5], e[5];
            float mx = -1e30f;
#pragma unroll
            for (int s = 0; s < 5; s++) { v[s] = omb[1][sm * ON + ob + s]; mx = fmaxf(mx, v[s]); }
            mx = fmaxf(mx, __shfl_xor(mx, 1));
            mx = fmaxf(mx, __shfl_xor(mx, 2));
            float se = 0.f;
#pragma unroll
            for (int s = 0; s < 5; s++) { e[s] = __expf(v[s] - mx); se += e[s]; }
            se += __shfl_xor(se, 1);
            se += __shfl_xor(se, 2);
            const float inv = 1.f / se;
#pragma unroll
            for (int s = 0; s < 5; s++) accs[s] += e[s] * inv;
        }
        __syncthreads();
    }
    // E2 (i=251): om(249), softmax(248)
    {
        if (w >= 6) {
            const bf16x8* f2p = (const bf16x8*)(sA2 + 2048);  // S2(249)
            bf16x8 f2[4], tO[4];
#pragma unroll
            for (int kt = 0; kt < 4; kt++) {
                f2[kt] = f2p[kt * 64 + lane];
                tO[kt] = loOr[kt * 64 + lane];
            }
            f32x4 aO = {0.f, 0.f, 0.f, 0.f};
#pragma unroll
            for (int kt = 0; kt < 4; kt++) {
                aO = __builtin_amdgcn_mfma_f32_16x16x32_bf16(f2[kt], hO[kt], aO, 0, 0, 0);
                aO = __builtin_amdgcn_mfma_f32_16x16x32_bf16(f2[kt], tO[kt], aO, 0, 0, 0);
            }
#pragma unroll
            for (int r = 0; r < 4; r++) {
                om[r] = ao * om[r] + (1.f - ao) * (bo + aO[r]);
                if (oval) omb[1][(q * 4 + r) * ON + ocol] = om[r];
            }
        }
        if (w == 0) {   // softmax step 248 from omb[0]
            float v[5], e[5];
            float mx = -1e30f;
#pragma unroll
            for (int s = 0; s < 5; s++) { v[s] = omb[0][sm * ON + ob + s]; mx = fmaxf(mx, v[s]); }
            mx = fmaxf(mx, __shfl_xor(mx, 1));
            mx = fmaxf(mx, __shfl_xor(mx, 2));
            float se = 0.f;
#pragma unroll
            for (int s = 0; s < 5; s++) { e[s] = __expf(v[s] - mx); se += e[s]; }
            se += __shfl_xor(se, 1);
            se += __shfl_xor(se, 2);
            const float inv = 1.f / se;
#pragma unroll
            for (int s = 0; s < 5; s++) accs[s] += e[s] * inv;
        }
        __syncthreads();
    }
    // E3: softmax(249) from omb[1], fused into output write
    if (w == 0) {
        float v[5], e[5];
        float mx = -1e30f;
#pragma unroll
        for (int s = 0; s < 5; s++) { v[s] = omb[1][sm * ON + ob + s]; mx = fmaxf(mx, v[s]); }
        mx = fmaxf(mx, __shfl_xor(mx, 1));
        mx = fmaxf(mx, __shfl_xor(mx, 2));
        float se = 0.f;
#pragma unroll
        for (int s = 0; s < 5; s++) { e[s] = __expf(v[s] - mx); se += e[s]; }
        se += __shfl_xor(se, 1);
        se += __shfl_xor(se, 2);
        const float inv = 1.f / se;
#pragma unroll
        for (int s = 0; s < 5; s++) out[(r0 + sm) * ON + ob + s] = accs[s] + e[s] * inv;
    }
    // spike rates
#pragma unroll
    for (int r = 0; r < 4; r++) {
        out[5120 + (r0 + q * 4 + r) * HN + col] = c1[r] * (1.f / 250.f);
        out[37888 + (r0 + q * 4 + r) * HN + col] = c2n[r] * (1.f / 250.f);
    }
}

// ---------------------------------------------------------------------------
extern "C" void kernel_launch(void* const* d_in, const int* in_sizes, int n_in,
                              void* d_out, int out_size, void* d_ws, size_t ws_size,
                              hipStream_t stream) {
    const float* x        = (const float*)d_in[0];
    const float* mask     = (const float*)d_in[1];
    const float* w_ih1    = (const float*)d_in[2];
    const float* b_ih1    = (const float*)d_in[3];
    const float* w_h1h1   = (const float*)d_in[4];
    const float* b_h1h1   = (const float*)d_in[5];
    const float* w_h1h2   = (const float*)d_in[6];
    const float* b_h1h2   = (const float*)d_in[7];
    const float* w_h2h2   = (const float*)d_in[8];
    const float* b_h2h2   = (const float*)d_in[9];
    const float* w_h2o    = (const float*)d_in[10];
    const float* b_h2o    = (const float*)d_in[11];
    const float* tau_adp1 = (const float*)d_in[12];
    const float* tau_adp2 = (const float*)d_in[13];
    const float* taum1    = (const float*)d_in[14];
    const float* taum2    = (const float*)d_in[15];
    const float* taumo    = (const float*)d_in[16];
    const float* h1m0     = (const float*)d_in[17];
    const float* h2m0     = (const float*)d_in[18];
    const float* om0      = (const float*)d_in[19];
    float* out = (float*)d_out;
    float* ws  = (float*)d_ws;

    float* xin = ws + XIN_OFF;
    unsigned short* wph = (unsigned short*)(ws + WPKH_OFF);
    unsigned short* wpl = (unsigned short*)(ws + WPKL_OFF);

    packw<<<352, 256, 0, stream>>>(w_ih1, wph, wpl);
    gemm_in<<<500, 512, 0, stream>>>(x, wph, wpl, b_ih1, b_h1h1, xin);
    snn_scan<<<16, 512, 0, stream>>>(xin, mask, w_h1h1, w_h1h2, b_h1h2, w_h2h2,
                                     b_h2h2, w_h2o, b_h2o, tau_adp1, tau_adp2,
                                     taum1, taum2, taumo, h1m0, h2m0, om0, out);
}